// Round 1
// baseline (361.032 us; speedup 1.0000x reference)
//
#include <hip/hip_runtime.h>

#define R_TOTAL 2097152
#define M_DEPTH 8
#define C_CH 16

// ---------------------------------------------------------------------------
// Repack [M, C, H, W] -> [M, H, W, C] so one texel's 16 channels = one 64B line.
// One thread per (m, y, x): 16 coalesced reads (per-c planes), 4 float4 stores.
// ---------------------------------------------------------------------------
__global__ __launch_bounds__(256) void repack_kernel(const float* __restrict__ src,
                                                     float* __restrict__ dst,
                                                     int lgHW) {
    int t = blockIdx.x * blockDim.x + threadIdx.x;   // index over M*H*W
    int HW = 1 << lgHW;
    int m  = t >> lgHW;
    int p  = t & (HW - 1);                           // y*W + x
    const float* s = src + (size_t)m * C_CH * HW + p;
    float v[C_CH];
#pragma unroll
    for (int c = 0; c < C_CH; ++c) v[c] = s[(size_t)c * HW];
    float4* d4 = (float4*)(dst + (size_t)t * C_CH);
#pragma unroll
    for (int r = 0; r < 4; ++r)
        d4[r] = make_float4(v[4 * r + 0], v[4 * r + 1], v[4 * r + 2], v[4 * r + 3]);
}

// ---------------------------------------------------------------------------
// Sampler on packed [M, H, W, C] textures. One thread per sample.
// ---------------------------------------------------------------------------
__global__ __launch_bounds__(256) void sample_packed(
    const float2* __restrict__ uv, const int* __restrict__ idcs,
    const float* __restrict__ sid, const float* __restrict__ tex0p,
    const float* __restrict__ tex1p, float* __restrict__ out) {
    int i = blockIdx.x * blockDim.x + threadIdx.x;

    float2 t  = uv[i];
    float  z  = sid[i];
    int which = idcs[i];

    const float* tex = (which == 0) ? tex0p : tex1p;
    int   Wm1 = (which == 0) ? 511 : 255;
    int   W   = Wm1 + 1;
    float fw  = (float)Wm1;

    float x = fminf(fmaxf((t.x + 1.0f) * 0.5f * fw, 0.0f), fw);
    float y = fminf(fmaxf((t.y + 1.0f) * 0.5f * fw, 0.0f), fw);
    float d = fminf(fmaxf((z + 1.0f) * 0.5f * 7.0f, 0.0f), 7.0f);

    int x0 = (int)x, y0 = (int)y, d0 = (int)d;
    int x1 = min(x0 + 1, Wm1), y1 = min(y0 + 1, Wm1), d1 = min(d0 + 1, 7);
    float wx = x - (float)x0, wy = y - (float)y0, wd = d - (float)d0;

    float acc[C_CH];
#pragma unroll
    for (int c = 0; c < C_CH; ++c) acc[c] = 0.0f;

    float w_d[2] = {1.0f - wd, wd};
    float w_y[2] = {1.0f - wy, wy};
    int   ds[2]  = {d0, d1};
    int   ys[2]  = {y0, y1};

#pragma unroll
    for (int a = 0; a < 2; ++a) {
#pragma unroll
        for (int b = 0; b < 2; ++b) {
            float w = w_d[a] * w_y[b];
            const float* base = tex + (size_t)(ds[a] * W + ys[b]) * W * C_CH;
            const float4* pa = (const float4*)(base + (size_t)x0 * C_CH);
            const float4* pb = (const float4*)(base + (size_t)x1 * C_CH);
#pragma unroll
            for (int r = 0; r < 4; ++r) {
                float4 va = pa[r];
                float4 vb = pb[r];
                acc[4 * r + 0] += w * (va.x + wx * (vb.x - va.x));
                acc[4 * r + 1] += w * (va.y + wx * (vb.y - va.y));
                acc[4 * r + 2] += w * (va.z + wx * (vb.z - va.z));
                acc[4 * r + 3] += w * (va.w + wx * (vb.w - va.w));
            }
        }
    }

#pragma unroll
    for (int c = 0; c < C_CH; ++c)
        out[(size_t)c * R_TOTAL + i] = acc[c];
}

// ---------------------------------------------------------------------------
// Fallback: sample directly from [M, C, H, W] (if workspace too small).
// ---------------------------------------------------------------------------
__global__ __launch_bounds__(256) void sample_direct(
    const float2* __restrict__ uv, const int* __restrict__ idcs,
    const float* __restrict__ sid, const float* __restrict__ tex0,
    const float* __restrict__ tex1, float* __restrict__ out) {
    int i = blockIdx.x * blockDim.x + threadIdx.x;

    float2 t  = uv[i];
    float  z  = sid[i];
    int which = idcs[i];

    const float* tex = (which == 0) ? tex0 : tex1;
    int   Wm1 = (which == 0) ? 511 : 255;
    int   W   = Wm1 + 1;
    float fw  = (float)Wm1;

    float x = fminf(fmaxf((t.x + 1.0f) * 0.5f * fw, 0.0f), fw);
    float y = fminf(fmaxf((t.y + 1.0f) * 0.5f * fw, 0.0f), fw);
    float d = fminf(fmaxf((z + 1.0f) * 0.5f * 7.0f, 0.0f), 7.0f);

    int x0 = (int)x, y0 = (int)y, d0 = (int)d;
    int x1 = min(x0 + 1, Wm1), y1 = min(y0 + 1, Wm1), d1 = min(d0 + 1, 7);
    float wx = x - (float)x0, wy = y - (float)y0, wd = d - (float)d0;

    float w_d[2] = {1.0f - wd, wd};
    float w_y[2] = {1.0f - wy, wy};
    int   ds[2]  = {d0, d1};
    int   ys[2]  = {y0, y1};

#pragma unroll
    for (int c = 0; c < C_CH; ++c) {
        float res = 0.0f;
#pragma unroll
        for (int a = 0; a < 2; ++a) {
#pragma unroll
            for (int b = 0; b < 2; ++b) {
                float w = w_d[a] * w_y[b];
                const float* base =
                    tex + ((size_t)ds[a] * C_CH + c) * W * W + (size_t)ys[b] * W;
                float va = base[x0];
                float vb = base[x1];
                res += w * (va + wx * (vb - va));
            }
        }
        out[(size_t)c * R_TOTAL + i] = res;
    }
}

extern "C" void kernel_launch(void* const* d_in, const int* in_sizes, int n_in,
                              void* d_out, int out_size, void* d_ws, size_t ws_size,
                              hipStream_t stream) {
    const float2* uv   = (const float2*)d_in[0];
    const int*    idcs = (const int*)d_in[1];
    const float*  sid  = (const float*)d_in[2];
    const float*  tex0 = (const float*)d_in[3];
    const float*  tex1 = (const float*)d_in[4];
    float*        out  = (float*)d_out;

    const size_t n0 = (size_t)M_DEPTH * C_CH * 512 * 512;  // 33,554,432 elems
    const size_t n1 = (size_t)M_DEPTH * C_CH * 256 * 256;  //  8,388,608 elems
    const size_t need = (n0 + n1) * sizeof(float);         // ~160 MiB

    if (ws_size >= need) {
        float* p0 = (float*)d_ws;
        float* p1 = p0 + n0;
        repack_kernel<<<(M_DEPTH * 512 * 512) / 256, 256, 0, stream>>>(tex0, p0, 18);
        repack_kernel<<<(M_DEPTH * 256 * 256) / 256, 256, 0, stream>>>(tex1, p1, 16);
        sample_packed<<<R_TOTAL / 256, 256, 0, stream>>>(uv, idcs, sid, p0, p1, out);
    } else {
        sample_direct<<<R_TOTAL / 256, 256, 0, stream>>>(uv, idcs, sid, tex0, tex1, out);
    }
}